// Round 7
// baseline (226.572 us; speedup 1.0000x reference)
//
#include <hip/hip_runtime.h>
#include <hip/hip_bf16.h>
#include <math.h>

// Problem constants: B=4, T=2048, K(head dim)=128, H=8
#define T_SEQ 2048
#define NH 8
#define DK 128
#define BATCH 4
#define KT 64     // attention KV tile
#define QTILE 128 // Q rows per block (4 waves x 32 rows)

// Q pre-scale: (1/sqrt(128)) * log2(e)  -> S feeds exp2 directly
#define QSCALE 0.1275174435f

typedef __attribute__((ext_vector_type(8))) short short8;
typedef __attribute__((ext_vector_type(4))) float floatx4;
typedef __attribute__((ext_vector_type(16))) float floatx16;
typedef __attribute__((ext_vector_type(4))) _Float16 half4;

typedef const __attribute__((address_space(1))) unsigned int gu32_t;
typedef __attribute__((address_space(3))) unsigned int lu32_t;

#if defined(__has_builtin)
#if __has_builtin(__builtin_amdgcn_exp2f)
#define EXP2F(x) __builtin_amdgcn_exp2f(x)
#endif
#endif
#ifndef EXP2F
#define EXP2F(x) exp2f(x)
#endif

__device__ __forceinline__ unsigned short f2bf(float f) {
  union { float f; unsigned u; } v; v.f = f;
  unsigned u = v.u;
  return (unsigned short)((u + 0x7fffu + ((u >> 16) & 1u)) >> 16);  // RNE
}

__device__ __forceinline__ float bf2f(unsigned short u) {
  union { unsigned u; float f; } v; v.u = ((unsigned)u) << 16;
  return v.f;
}

__device__ __forceinline__ unsigned short f2h(float f) {
  union { _Float16 h; unsigned short u; } v; v.h = (_Float16)f;
  return v.u;
}

__device__ __forceinline__ unsigned pk2bf(float a, float b) {
  __hip_bfloat162 h = __float22bfloat162_rn(make_float2(a, b));
  return *(unsigned*)&h;   // low 16 = a, high 16 = b
}

// ---------------------------------------------------------------------------
// Kernel 0: prep — x -> bf16 (xb) and Wq*QSCALE/Wk/Wv -> bf16 (Wb).
// Both live in the attn ws region (dead until attn_kernel runs).
// grid = 1024 (x) + 384 (W) blocks, 4 elems/thread.
// ---------------------------------------------------------------------------
__global__ __launch_bounds__(256) void prep1_kernel(
    const float* __restrict__ x, const float* __restrict__ Wq,
    const float* __restrict__ Wk, const float* __restrict__ Wv,
    unsigned short* __restrict__ xb, unsigned short* __restrict__ Wb)
{
  int bid = blockIdx.x;
  if (bid < 1024) {
    int i = (bid * 256 + threadIdx.x) * 4;        // x: 1,048,576 elems
    float4 v = *(const float4*)(x + i);
    uint2 o = make_uint2(pk2bf(v.x, v.y), pk2bf(v.z, v.w));
    *(uint2*)(xb + i) = o;
  } else {
    int j = ((bid - 1024) * 256 + threadIdx.x) * 4;   // 0..393215
    int which = j >> 17;                              // /131072
    int jj = j & 131071;
    const float* W = (which == 0) ? Wq : ((which == 1) ? Wk : Wv);
    float4 v = *(const float4*)(W + jj);
    float s = (which == 0) ? QSCALE : 1.0f;
    uint2 o = make_uint2(pk2bf(v.x * s, v.y * s), pk2bf(v.z * s, v.w * s));
    *(uint2*)(Wb + j) = o;
  }
}

// ---------------------------------------------------------------------------
// Kernel 1: QKV projection v2, LDS-free, all-bf16. Each block computes the
// Q, K AND V 128x128 tiles for its (row-block, col-block), reusing the x
// A-fragments in registers across the three weights. grid = (8, 64).
// Q,K -> [B][H][T][128] bf16 (Q pre-scaled); V -> [B][H][128][T] fp16.
// ---------------------------------------------------------------------------
__global__ __launch_bounds__(256) void qkv_proj_kernel(
    const unsigned short* __restrict__ xb, const unsigned short* __restrict__ Wb,
    unsigned short* __restrict__ Qw, unsigned short* __restrict__ Kw,
    unsigned short* __restrict__ Vt)
{
  int nb = blockIdx.x * 128;       // col base within 1024
  int mb = blockIdx.y * 128;       // row base within 8192
  int t = threadIdx.x, wave = t >> 6, lane = t & 63;
  int n = lane & 15, q = lane >> 4;

  // x A-fragments for this wave's 32 rows (bf16, read once, used 3x)
  short8 xa[2][4];
  #pragma unroll
  for (int rg = 0; rg < 2; ++rg) {
    const unsigned short* xr = xb + (size_t)(mb + wave*32 + rg*16 + n) * DK;
    #pragma unroll
    for (int kc = 0; kc < 4; ++kc)
      xa[rg][kc] = *(const short8*)(xr + kc*32 + q*8);
  }

  // Q (w=0) and K (w=1)
  for (int w = 0; w < 2; ++w) {
    const unsigned short* Wp = Wb + (size_t)w * (NH * DK * DK);
    unsigned short* Ow = (w == 0) ? Qw : Kw;
    floatx4 acc[2][8];
    #pragma unroll
    for (int rg = 0; rg < 2; ++rg)
      #pragma unroll
      for (int cg = 0; cg < 8; ++cg)
        acc[rg][cg] = (floatx4){0.f, 0.f, 0.f, 0.f};
    #pragma unroll
    for (int kc = 0; kc < 4; ++kc)
      #pragma unroll
      for (int cg = 0; cg < 8; ++cg) {
        short8 bk = *(const short8*)(Wp + (size_t)(nb + cg*16 + n)*DK + kc*32 + q*8);
        acc[0][cg] = __builtin_amdgcn_mfma_f32_16x16x32_bf16(xa[0][kc], bk, acc[0][cg], 0, 0, 0);
        acc[1][cg] = __builtin_amdgcn_mfma_f32_16x16x32_bf16(xa[1][kc], bk, acc[1][cg], 0, 0, 0);
      }
    #pragma unroll
    for (int rg = 0; rg < 2; ++rg)
      #pragma unroll
      for (int cg = 0; cg < 8; ++cg)
        #pragma unroll
        for (int r = 0; r < 4; ++r) {
          int m    = mb + wave*32 + rg*16 + q*4 + r;
          int ncol = nb + cg*16 + n;
          int bb = m >> 11, tt = m & (T_SEQ - 1);
          int hh = ncol >> 7, dd = ncol & 127;
          Ow[(((size_t)(bb*NH + hh))*T_SEQ + tt)*DK + dd] = f2bf(acc[rg][cg][r]);
        }
  }

  // V: transposed output via swapped operands (A=W-frag, B=x-frag), fp16 out
  {
    const unsigned short* Wp = Wb + (size_t)2 * (NH * DK * DK);
    floatx4 accv[8][2];
    #pragma unroll
    for (int mt = 0; mt < 8; ++mt)
      #pragma unroll
      for (int nt = 0; nt < 2; ++nt)
        accv[mt][nt] = (floatx4){0.f, 0.f, 0.f, 0.f};
    #pragma unroll
    for (int kc = 0; kc < 4; ++kc)
      #pragma unroll
      for (int mt = 0; mt < 8; ++mt) {
        short8 wa = *(const short8*)(Wp + (size_t)(nb + mt*16 + n)*DK + kc*32 + q*8);
        accv[mt][0] = __builtin_amdgcn_mfma_f32_16x16x32_bf16(wa, xa[0][kc], accv[mt][0], 0, 0, 0);
        accv[mt][1] = __builtin_amdgcn_mfma_f32_16x16x32_bf16(wa, xa[1][kc], accv[mt][1], 0, 0, 0);
      }
    #pragma unroll
    for (int mt = 0; mt < 8; ++mt)
      #pragma unroll
      for (int nt = 0; nt < 2; ++nt)
        #pragma unroll
        for (int r = 0; r < 4; ++r) {
          int ncol = nb + mt*16 + q*4 + r;                 // (h,d)
          int m    = mb + wave*32 + nt*16 + n;             // (b,t)
          int bb = m >> 11, tt = m & (T_SEQ - 1);
          int hh = ncol >> 7, dd = ncol & 127;
          Vt[(((size_t)(bb*NH + hh))*DK + dd)*T_SEQ + tt] = f2h(accv[mt][nt][r]);
        }
  }
}

// ---------------------------------------------------------------------------
// Kernel 2: flash attention (UNCHANGED from round 6 — 93.7 µs, MfmaUtil 48%).
// Double-buffered K/V via global_load_lds (XOR-swizzled chunks); QK^T
// computed transposed (32x32x16 bf16) so exp2'd C-regs are directly the
// A-frags of the 32x32x8 f16 PV MFMA. No P LDS round-trip.
// ---------------------------------------------------------------------------
__global__ __launch_bounds__(256, 2) void attn_kernel(
    const unsigned short* __restrict__ Qw, const unsigned short* __restrict__ Kw,
    const unsigned short* __restrict__ Vt, unsigned short* __restrict__ attn_out)
{
  __shared__ __align__(16) unsigned short Ks[2][KT * DK];   // 2 x 16 KB
  __shared__ __align__(16) unsigned short Vs[2][DK * KT];   // 2 x 16 KB
  int bid = blockIdx.x;
  int qt = bid & 15, h = (bid >> 4) & 7, b = bid >> 7;
  size_t base = ((size_t)(b * NH + h)) * T_SEQ * DK;
  const unsigned short* Qb = Qw + base;
  const unsigned short* Kb = Kw + base;
  const unsigned short* Vb = Vt + base;   // [128][2048] fp16
  int t = threadIdx.x, w = t >> 6, lane = t & 63;
  int l31 = lane & 31, l15 = lane & 15, l7 = lane & 7, hi = lane >> 5;

  short8 qf[8];
  {
    const unsigned short* qr = Qb + (size_t)(qt*QTILE + w*32 + l31) * DK;
    #pragma unroll
    for (int kc = 0; kc < 8; ++kc)
      qf[kc] = *(const short8*)(qr + kc*16 + hi*8);
  }
  floatx16 Oacc[4];
  #pragma unroll
  for (int dt = 0; dt < 4; ++dt)
    #pragma unroll
    for (int r = 0; r < 16; ++r) Oacc[dt][r] = 0.f;
  float lp = 0.f;

  int kkey_lo = lane >> 4;
  int kck     = lane & 15;
  int vd_lo   = lane >> 3;
  int vck     = lane & 7;
  int cv      = vck ^ vd_lo;

  #define STAGE(KTI, BUFI)                                                      \
    {                                                                           \
      _Pragma("unroll")                                                         \
      for (int j = 0; j < 4; ++j) {                                             \
        int inst = w*4 + j;                                                     \
        int key = inst*4 + kkey_lo;                                             \
        int ck = kck ^ (key & 15);                                              \
        __builtin_amdgcn_global_load_lds(                                       \
            (gu32_t*)(Kb + ((size_t)((KTI)*KT + key))*DK + ck*8),               \
            (lu32_t*)(&Ks[BUFI][inst*512]), 16, 0, 0);                          \
        int d = inst*8 + vd_lo;                                                 \
        __builtin_amdgcn_global_load_lds(                                       \
            (gu32_t*)(Vb + (size_t)d*T_SEQ + (KTI)*KT + cv*8),                  \
            (lu32_t*)(&Vs[BUFI][inst*512]), 16, 0, 0);                          \
      }                                                                         \
    }

  STAGE(0, 0);

  for (int kt = 0; kt < T_SEQ / KT; ++kt) {
    __syncthreads();
    int buf = kt & 1;
    if (kt + 1 < T_SEQ / KT) STAGE(kt + 1, buf ^ 1);

    const unsigned short* KsL = &Ks[buf][0];
    const unsigned short* VsL = &Vs[buf][0];

    floatx16 st0, st1;
    #pragma unroll
    for (int r = 0; r < 16; ++r) { st0[r] = 0.f; st1[r] = 0.f; }
    #pragma unroll
    for (int kc = 0; kc < 8; ++kc) {
      int cp = (2*kc + hi) ^ l15;
      short8 ak0 = *(const short8*)&KsL[(      l31)*DK + cp*8];
      short8 ak1 = *(const short8*)&KsL[(32 + l31)*DK + cp*8];
      st0 = __builtin_amdgcn_mfma_f32_32x32x16_bf16(ak0, qf[kc], st0, 0, 0, 0);
      st1 = __builtin_amdgcn_mfma_f32_32x32x16_bf16(ak1, qf[kc], st1, 0, 0, 0);
    }
    #pragma unroll
    for (int g = 0; g < 2; ++g) {
      const floatx16& st = g ? st1 : st0;
      float e[16];
      #pragma unroll
      for (int r = 0; r < 16; ++r) e[r] = EXP2F(st[r]);
      float s = 0.f;
      #pragma unroll
      for (int r = 0; r < 16; ++r) s += e[r];
      lp += s;
      #pragma unroll
      for (int m = 0; m < 4; ++m) {
        half4 ap;
        ap[0] = (_Float16)e[4*m];     ap[1] = (_Float16)e[4*m + 1];
        ap[2] = (_Float16)e[4*m + 2]; ap[3] = (_Float16)e[4*m + 3];
        int cp = (4*g + m) ^ l7;
        #pragma unroll
        for (int dt = 0; dt < 4; ++dt) {
          int d = dt*32 + l31;
          half4 bv = *(const half4*)&VsL[d*KT + cp*8 + hi*4];
          Oacc[dt] = __builtin_amdgcn_mfma_f32_32x32x8f16(ap, bv, Oacc[dt], 0, 0, 0);
        }
      }
    }
  }
  float lpt = lp + __shfl_xor(lp, 32, 64);
  float rinv = 1.0f / lpt;
  float ri[16];
  #pragma unroll
  for (int r = 0; r < 16; ++r) {
    int row = (r & 3) + 8*(r >> 2) + 4*hi;
    ri[r] = __shfl(rinv, row, 64);
  }
  #pragma unroll
  for (int dt = 0; dt < 4; ++dt)
    #pragma unroll
    for (int r = 0; r < 16; ++r) {
      int row = (r & 3) + 8*(r >> 2) + 4*hi;
      int trow = qt*QTILE + w*32 + row;
      int col  = h*DK + dt*32 + l31;
      attn_out[((size_t)b*T_SEQ + trow)*1024 + col] = f2bf(Oacc[dt][r] * ri[r]);
    }
}

// ---------------------------------------------------------------------------
// Kernel 3a: split Wu into hi+lo bf16 (into the dead Qw region).
// ---------------------------------------------------------------------------
__global__ __launch_bounds__(256) void wu_prep_kernel(
    const float* __restrict__ Wu, unsigned short* __restrict__ wh,
    unsigned short* __restrict__ wl)
{
  int i = blockIdx.x * 256 + threadIdx.x;   // 131072 total
  float w = Wu[i];
  unsigned short hi = f2bf(w);
  wh[i] = hi;
  wl[i] = f2bf(w - bf2f(hi));
}

// ---------------------------------------------------------------------------
// Kernel 3b: out = attn(8192,1024)bf16 @ (Whi+Wlo)^T + bu. LDS-free.
// grid = 512 blocks (16 rows each -> 2 blocks/CU), 256 threads.
// Wave owns a 32-col slice of the 128 output cols.
// ---------------------------------------------------------------------------
__global__ __launch_bounds__(256) void out_proj_kernel(
    const unsigned short* __restrict__ attnb, const unsigned short* __restrict__ wh,
    const unsigned short* __restrict__ wl, const float* __restrict__ bu,
    float* __restrict__ out)
{
  int mb = blockIdx.x * 16;
  int t = threadIdx.x, wave = t >> 6, lane = t & 63;
  int n = lane & 15, q = lane >> 4;
  int nb2 = wave * 32;
  floatx4 acc[2];
  acc[0] = (floatx4){0.f,0.f,0.f,0.f};
  acc[1] = (floatx4){0.f,0.f,0.f,0.f};
  const unsigned short* ap = attnb + (size_t)(mb + n) * 1024;
  #pragma unroll 4
  for (int kc = 0; kc < 32; ++kc) {
    int ko = kc*32 + q*8;
    short8 a0 = *(const short8*)(ap + ko);
    #pragma unroll
    for (int cg = 0; cg < 2; ++cg) {
      const size_t wrow = (size_t)(nb2 + cg*16 + n) * 1024 + ko;
      short8 bh = *(const short8*)(wh + wrow);
      short8 bl = *(const short8*)(wl + wrow);
      acc[cg] = __builtin_amdgcn_mfma_f32_16x16x32_bf16(a0, bh, acc[cg], 0, 0, 0);
      acc[cg] = __builtin_amdgcn_mfma_f32_16x16x32_bf16(a0, bl, acc[cg], 0, 0, 0);
    }
  }
  #pragma unroll
  for (int cg = 0; cg < 2; ++cg)
    #pragma unroll
    for (int r = 0; r < 4; ++r) {
      int m = mb + q*4 + r;
      int c = nb2 + cg*16 + n;
      out[(size_t)m * 128 + c] = acc[cg][r] + bu[c];
    }
}

// ---------------------------------------------------------------------------
extern "C" void kernel_launch(void* const* d_in, const int* in_sizes, int n_in,
                              void* d_out, int out_size, void* d_ws, size_t ws_size,
                              hipStream_t stream) {
  const float* x  = (const float*)d_in[0];
  const float* Wq = (const float*)d_in[1];
  const float* Wk = (const float*)d_in[2];
  const float* Wv = (const float*)d_in[3];
  const float* Wu = (const float*)d_in[4];
  const float* bu = (const float*)d_in[5];
  float* out = (float*)d_out;

  const size_t NE = (size_t)BATCH * NH * T_SEQ * DK;  // 8,388,608 elems
  unsigned short* Qw = (unsigned short*)d_ws;
  unsigned short* Kw = Qw + NE;
  unsigned short* Vt = Kw + NE;
  unsigned short* attn = Vt + NE;
  if (ws_size < 4 * NE * sizeof(unsigned short)) return;

  // Wb (786 KB) + xb (2 MB) live in the attn region until attn_kernel runs.
  unsigned short* Wb = attn;                          // 3 * 131072 elems
  unsigned short* xb = attn + 3 * (NH * DK * DK);     // 1,048,576 elems
  // Wu hi/lo reuse the Qw region (dead after attn_kernel).
  unsigned short* WuH = Qw;
  unsigned short* WuL = Qw + NH * DK * DK;            // 131072

  prep1_kernel<<<1408, 256, 0, stream>>>(x, Wq, Wk, Wv, xb, Wb);
  dim3 g1(8, 64);
  qkv_proj_kernel<<<g1, 256, 0, stream>>>(xb, Wb, Qw, Kw, Vt);
  attn_kernel<<<BATCH * NH * (T_SEQ / QTILE), 256, 0, stream>>>(Qw, Kw, Vt, attn);
  wu_prep_kernel<<<512, 256, 0, stream>>>(Wu, WuH, WuL);
  out_proj_kernel<<<BATCH * T_SEQ / 16, 256, 0, stream>>>(attn, WuH, WuL, bu, out);
}

// Round 8
// 219.058 us; speedup vs baseline: 1.0343x; 1.0343x over previous
//
#include <hip/hip_runtime.h>
#include <hip/hip_bf16.h>
#include <math.h>

// Problem constants: B=4, T=2048, K(head dim)=128, H=8
#define T_SEQ 2048
#define NH 8
#define DK 128
#define BATCH 4
#define KT 64     // attention KV tile
#define QTILE 128 // Q rows per block (4 waves x 32 rows)

// Q pre-scale: (1/sqrt(128)) * log2(e)  -> S feeds exp2 directly
#define QSCALE 0.1275174435f

typedef __attribute__((ext_vector_type(8))) short short8;
typedef __attribute__((ext_vector_type(4))) float floatx4;
typedef __attribute__((ext_vector_type(16))) float floatx16;
typedef __attribute__((ext_vector_type(8))) _Float16 half8;

typedef const __attribute__((address_space(1))) unsigned int gu32_t;
typedef __attribute__((address_space(3))) unsigned int lu32_t;

#if defined(__has_builtin)
#if __has_builtin(__builtin_amdgcn_exp2f)
#define EXP2F(x) __builtin_amdgcn_exp2f(x)
#endif
#endif
#ifndef EXP2F
#define EXP2F(x) exp2f(x)
#endif

__device__ __forceinline__ unsigned short f2bf(float f) {
  union { float f; unsigned u; } v; v.f = f;
  unsigned u = v.u;
  return (unsigned short)((u + 0x7fffu + ((u >> 16) & 1u)) >> 16);  // RNE
}

__device__ __forceinline__ unsigned short f2h(float f) {
  union { _Float16 h; unsigned short u; } v; v.h = (_Float16)f;
  return v.u;
}

__device__ __forceinline__ unsigned pk2bf(float a, float b) {
  __hip_bfloat162 h = __float22bfloat162_rn(make_float2(a, b));
  return *(unsigned*)&h;   // low 16 = a, high 16 = b
}

__device__ __forceinline__ unsigned pkh(float a, float b) {
  union { _Float16 h[2]; unsigned u; } v;
  v.h[0] = (_Float16)a; v.h[1] = (_Float16)b;
  return v.u;
}

// ---------------------------------------------------------------------------
// Kernel 0: prep — x -> bf16 (xb) and Wq*QSCALE/Wk/Wv -> bf16 (Wb).
// Both live in the attn ws region (dead until attn_kernel runs).
// ---------------------------------------------------------------------------
__global__ __launch_bounds__(256) void prep1_kernel(
    const float* __restrict__ x, const float* __restrict__ Wq,
    const float* __restrict__ Wk, const float* __restrict__ Wv,
    unsigned short* __restrict__ xb, unsigned short* __restrict__ Wb)
{
  int bid = blockIdx.x;
  if (bid < 1024) {
    int i = (bid * 256 + threadIdx.x) * 4;        // x: 1,048,576 elems
    float4 v = *(const float4*)(x + i);
    uint2 o = make_uint2(pk2bf(v.x, v.y), pk2bf(v.z, v.w));
    *(uint2*)(xb + i) = o;
  } else {
    int j = ((bid - 1024) * 256 + threadIdx.x) * 4;   // 0..393215
    int which = j >> 17;                              // /131072
    int jj = j & 131071;
    const float* W = (which == 0) ? Wq : ((which == 1) ? Wk : Wv);
    float4 v = *(const float4*)(W + jj);
    float s = (which == 0) ? QSCALE : 1.0f;
    uint2 o = make_uint2(pk2bf(v.x * s, v.y * s), pk2bf(v.z * s, v.w * s));
    *(uint2*)(Wb + j) = o;
  }
}

// ---------------------------------------------------------------------------
// Kernel 1: QKV projection, LDS-free, all-bf16. Each block computes the
// Q, K AND V 128x128 tiles for its (row-block, col-block), reusing the x
// A-fragments in registers across the three weights. grid = (8, 64).
// Q,K -> [B][H][T][128] bf16 (Q pre-scaled); V -> [B][H][128][T] fp16.
// ---------------------------------------------------------------------------
__global__ __launch_bounds__(256) void qkv_proj_kernel(
    const unsigned short* __restrict__ xb, const unsigned short* __restrict__ Wb,
    unsigned short* __restrict__ Qw, unsigned short* __restrict__ Kw,
    unsigned short* __restrict__ Vt)
{
  int nb = blockIdx.x * 128;       // col base within 1024
  int mb = blockIdx.y * 128;       // row base within 8192
  int t = threadIdx.x, wave = t >> 6, lane = t & 63;
  int n = lane & 15, q = lane >> 4;

  short8 xa[2][4];
  #pragma unroll
  for (int rg = 0; rg < 2; ++rg) {
    const unsigned short* xr = xb + (size_t)(mb + wave*32 + rg*16 + n) * DK;
    #pragma unroll
    for (int kc = 0; kc < 4; ++kc)
      xa[rg][kc] = *(const short8*)(xr + kc*32 + q*8);
  }

  for (int w = 0; w < 2; ++w) {
    const unsigned short* Wp = Wb + (size_t)w * (NH * DK * DK);
    unsigned short* Ow = (w == 0) ? Qw : Kw;
    floatx4 acc[2][8];
    #pragma unroll
    for (int rg = 0; rg < 2; ++rg)
      #pragma unroll
      for (int cg = 0; cg < 8; ++cg)
        acc[rg][cg] = (floatx4){0.f, 0.f, 0.f, 0.f};
    #pragma unroll
    for (int kc = 0; kc < 4; ++kc)
      #pragma unroll
      for (int cg = 0; cg < 8; ++cg) {
        short8 bk = *(const short8*)(Wp + (size_t)(nb + cg*16 + n)*DK + kc*32 + q*8);
        acc[0][cg] = __builtin_amdgcn_mfma_f32_16x16x32_bf16(xa[0][kc], bk, acc[0][cg], 0, 0, 0);
        acc[1][cg] = __builtin_amdgcn_mfma_f32_16x16x32_bf16(xa[1][kc], bk, acc[1][cg], 0, 0, 0);
      }
    #pragma unroll
    for (int rg = 0; rg < 2; ++rg)
      #pragma unroll
      for (int cg = 0; cg < 8; ++cg)
        #pragma unroll
        for (int r = 0; r < 4; ++r) {
          int m    = mb + wave*32 + rg*16 + q*4 + r;
          int ncol = nb + cg*16 + n;
          int bb = m >> 11, tt = m & (T_SEQ - 1);
          int hh = ncol >> 7, dd = ncol & 127;
          Ow[(((size_t)(bb*NH + hh))*T_SEQ + tt)*DK + dd] = f2bf(acc[rg][cg][r]);
        }
  }

  {
    const unsigned short* Wp = Wb + (size_t)2 * (NH * DK * DK);
    floatx4 accv[8][2];
    #pragma unroll
    for (int mt = 0; mt < 8; ++mt)
      #pragma unroll
      for (int nt = 0; nt < 2; ++nt)
        accv[mt][nt] = (floatx4){0.f, 0.f, 0.f, 0.f};
    #pragma unroll
    for (int kc = 0; kc < 4; ++kc)
      #pragma unroll
      for (int mt = 0; mt < 8; ++mt) {
        short8 wa = *(const short8*)(Wp + (size_t)(nb + mt*16 + n)*DK + kc*32 + q*8);
        accv[mt][0] = __builtin_amdgcn_mfma_f32_16x16x32_bf16(wa, xa[0][kc], accv[mt][0], 0, 0, 0);
        accv[mt][1] = __builtin_amdgcn_mfma_f32_16x16x32_bf16(wa, xa[1][kc], accv[mt][1], 0, 0, 0);
      }
    #pragma unroll
    for (int mt = 0; mt < 8; ++mt)
      #pragma unroll
      for (int nt = 0; nt < 2; ++nt)
        #pragma unroll
        for (int r = 0; r < 4; ++r) {
          int ncol = nb + mt*16 + q*4 + r;                 // (h,d)
          int m    = mb + wave*32 + nt*16 + n;             // (b,t)
          int bb = m >> 11, tt = m & (T_SEQ - 1);
          int hh = ncol >> 7, dd = ncol & 127;
          Vt[(((size_t)(bb*NH + hh))*DK + dd)*T_SEQ + tt] = f2h(accv[mt][nt][r]);
        }
  }
}

// ---------------------------------------------------------------------------
// Kernel 2: flash attention. Double-buffered K/V via global_load_lds (XOR
// swizzle). QK^T transposed (32x32x16 bf16). PV now FULL-RATE 32x32x16 f16:
// a shfl_xor(32) pairs-exchange turns the exp2'd C-regs into K=16 A-frags,
// and half8 (b128) V reads make every 8-lane beat hit all 32 banks.
// ---------------------------------------------------------------------------
__global__ __launch_bounds__(256, 2) void attn_kernel(
    const unsigned short* __restrict__ Qw, const unsigned short* __restrict__ Kw,
    const unsigned short* __restrict__ Vt, unsigned short* __restrict__ attn_out)
{
  __shared__ __align__(16) unsigned short Ks[2][KT * DK];   // 2 x 16 KB
  __shared__ __align__(16) unsigned short Vs[2][DK * KT];   // 2 x 16 KB
  int bid = blockIdx.x;
  int qt = bid & 15, h = (bid >> 4) & 7, b = bid >> 7;
  size_t base = ((size_t)(b * NH + h)) * T_SEQ * DK;
  const unsigned short* Qb = Qw + base;
  const unsigned short* Kb = Kw + base;
  const unsigned short* Vb = Vt + base;   // [128][2048] fp16
  int t = threadIdx.x, w = t >> 6, lane = t & 63;
  int l31 = lane & 31, l15 = lane & 15, hi = lane >> 5;
  bool hb = (hi != 0);

  short8 qf[8];
  {
    const unsigned short* qr = Qb + (size_t)(qt*QTILE + w*32 + l31) * DK;
    #pragma unroll
    for (int kc = 0; kc < 8; ++kc)
      qf[kc] = *(const short8*)(qr + kc*16 + hi*8);
  }
  floatx16 Oacc[4];
  #pragma unroll
  for (int dt = 0; dt < 4; ++dt)
    #pragma unroll
    for (int r = 0; r < 16; ++r) Oacc[dt][r] = 0.f;
  float lp = 0.f;

  int kkey_lo = lane >> 4;
  int kck     = lane & 15;
  int vd_lo   = lane >> 3;
  int vck     = lane & 7;
  int cv      = vck ^ vd_lo;

  #define STAGE(KTI, BUFI)                                                      \
    {                                                                           \
      _Pragma("unroll")                                                         \
      for (int j = 0; j < 4; ++j) {                                             \
        int inst = w*4 + j;                                                     \
        int key = inst*4 + kkey_lo;                                             \
        int ck = kck ^ (key & 15);                                              \
        __builtin_amdgcn_global_load_lds(                                       \
            (gu32_t*)(Kb + ((size_t)((KTI)*KT + key))*DK + ck*8),               \
            (lu32_t*)(&Ks[BUFI][inst*512]), 16, 0, 0);                          \
        int d = inst*8 + vd_lo;                                                 \
        __builtin_amdgcn_global_load_lds(                                       \
            (gu32_t*)(Vb + (size_t)d*T_SEQ + (KTI)*KT + cv*8),                  \
            (lu32_t*)(&Vs[BUFI][inst*512]), 16, 0, 0);                          \
      }                                                                         \
    }

  STAGE(0, 0);

  for (int kt = 0; kt < T_SEQ / KT; ++kt) {
    __syncthreads();
    int buf = kt & 1;
    if (kt + 1 < T_SEQ / KT) STAGE(kt + 1, buf ^ 1);

    const unsigned short* KsL = &Ks[buf][0];
    const unsigned short* VsL = &Vs[buf][0];

    floatx16 st0, st1;
    #pragma unroll
    for (int r = 0; r < 16; ++r) { st0[r] = 0.f; st1[r] = 0.f; }
    #pragma unroll
    for (int kc = 0; kc < 8; ++kc) {
      int cp = (2*kc + hi) ^ l15;
      short8 ak0 = *(const short8*)&KsL[(      l31)*DK + cp*8];
      short8 ak1 = *(const short8*)&KsL[(32 + l31)*DK + cp*8];
      st0 = __builtin_amdgcn_mfma_f32_32x32x16_bf16(ak0, qf[kc], st0, 0, 0, 0);
      st1 = __builtin_amdgcn_mfma_f32_32x32x16_bf16(ak1, qf[kc], st1, 0, 0, 0);
    }
    // P = exp2(S^T); build K=16 f16 A-frags via one pairs-exchange with the
    // partner lane (same Q-row, other hi): reg r holds key 8(r>>2)+4hi+(r&3).
    #pragma unroll
    for (int g = 0; g < 2; ++g) {
      const floatx16& st = g ? st1 : st0;
      float e[16];
      #pragma unroll
      for (int r = 0; r < 16; ++r) e[r] = EXP2F(st[r]);
      float s = 0.f;
      #pragma unroll
      for (int r = 0; r < 16; ++r) s += e[r];
      lp += s;
      unsigned p[8];
      #pragma unroll
      for (int i = 0; i < 8; ++i) p[i] = pkh(e[2*i], e[2*i + 1]);
      // p[4m+0..1] = keys 16m+4hi+{0..3}; p[4m+2..3] = keys 16m+8+4hi+{0..3}
      #pragma unroll
      for (int m = 0; m < 2; ++m) {
        unsigned lo0 = p[4*m], lo1 = p[4*m + 1];
        unsigned up0 = p[4*m + 2], up1 = p[4*m + 3];
        unsigned s0 = hb ? lo0 : up0;     // hi=0 sends keys 8-11; hi=1 sends 4-7
        unsigned s1 = hb ? lo1 : up1;
        unsigned r0 = __shfl_xor(s0, 32, 64);
        unsigned r1 = __shfl_xor(s1, 32, 64);
        union { half8 hv; unsigned u[4]; } fm;
        fm.u[0] = hb ? r0 : lo0;          // k = 8hi + 0,1
        fm.u[1] = hb ? r1 : lo1;          // k = 8hi + 2,3
        fm.u[2] = hb ? up0 : r0;          // k = 8hi + 4,5
        fm.u[3] = hb ? up1 : r1;          // k = 8hi + 6,7
        int cp = (4*g + 2*m + hi) ^ (l31 & 7);
        #pragma unroll
        for (int dt = 0; dt < 4; ++dt) {
          int d = dt*32 + l31;
          half8 bv = *(const half8*)&VsL[d*KT + cp*8];
          Oacc[dt] = __builtin_amdgcn_mfma_f32_32x32x16_f16(fm.hv, bv, Oacc[dt], 0, 0, 0);
        }
      }
    }
  }
  float lpt = lp + __shfl_xor(lp, 32, 64);
  float rinv = 1.0f / lpt;
  float ri[16];
  #pragma unroll
  for (int r = 0; r < 16; ++r) {
    int row = (r & 3) + 8*(r >> 2) + 4*hi;
    ri[r] = __shfl(rinv, row, 64);
  }
  #pragma unroll
  for (int dt = 0; dt < 4; ++dt)
    #pragma unroll
    for (int r = 0; r < 16; ++r) {
      int row = (r & 3) + 8*(r >> 2) + 4*hi;
      int trow = qt*QTILE + w*32 + row;
      int col  = h*DK + dt*32 + l31;
      attn_out[((size_t)b*T_SEQ + trow)*1024 + col] = f2bf(Oacc[dt][r] * ri[r]);
    }
}

// ---------------------------------------------------------------------------
// Kernel 3: out = attn(8192,1024)bf16 @ Wu^T + bu. LDS-free; Wu read fp32
// from L2 and converted to bf16 in-register (single bf16: err ~2e-4 max).
// grid = 512 blocks (16 rows each), 256 threads.
// ---------------------------------------------------------------------------
__global__ __launch_bounds__(256) void out_proj_kernel(
    const unsigned short* __restrict__ attnb, const float* __restrict__ Wu,
    const float* __restrict__ bu, float* __restrict__ out)
{
  int mb = blockIdx.x * 16;
  int t = threadIdx.x, wave = t >> 6, lane = t & 63;
  int n = lane & 15, q = lane >> 4;
  int nb2 = wave * 32;
  floatx4 acc[2];
  acc[0] = (floatx4){0.f,0.f,0.f,0.f};
  acc[1] = (floatx4){0.f,0.f,0.f,0.f};
  const unsigned short* ap = attnb + (size_t)(mb + n) * 1024;
  #pragma unroll 4
  for (int kc = 0; kc < 32; ++kc) {
    int ko = kc*32 + q*8;
    short8 a0 = *(const short8*)(ap + ko);
    #pragma unroll
    for (int cg = 0; cg < 2; ++cg) {
      const float* wr = Wu + (size_t)(nb2 + cg*16 + n) * 1024 + ko;
      float4 w0 = *(const float4*)(wr);
      float4 w1 = *(const float4*)(wr + 4);
      union { short8 s; unsigned u[4]; } bw;
      bw.u[0] = pk2bf(w0.x, w0.y); bw.u[1] = pk2bf(w0.z, w0.w);
      bw.u[2] = pk2bf(w1.x, w1.y); bw.u[3] = pk2bf(w1.z, w1.w);
      acc[cg] = __builtin_amdgcn_mfma_f32_16x16x32_bf16(a0, bw.s, acc[cg], 0, 0, 0);
    }
  }
  #pragma unroll
  for (int cg = 0; cg < 2; ++cg)
    #pragma unroll
    for (int r = 0; r < 4; ++r) {
      int m = mb + q*4 + r;
      int c = nb2 + cg*16 + n;
      out[(size_t)m * 128 + c] = acc[cg][r] + bu[c];
    }
}

// ---------------------------------------------------------------------------
extern "C" void kernel_launch(void* const* d_in, const int* in_sizes, int n_in,
                              void* d_out, int out_size, void* d_ws, size_t ws_size,
                              hipStream_t stream) {
  const float* x  = (const float*)d_in[0];
  const float* Wq = (const float*)d_in[1];
  const float* Wk = (const float*)d_in[2];
  const float* Wv = (const float*)d_in[3];
  const float* Wu = (const float*)d_in[4];
  const float* bu = (const float*)d_in[5];
  float* out = (float*)d_out;

  const size_t NE = (size_t)BATCH * NH * T_SEQ * DK;  // 8,388,608 elems
  unsigned short* Qw = (unsigned short*)d_ws;
  unsigned short* Kw = Qw + NE;
  unsigned short* Vt = Kw + NE;
  unsigned short* attn = Vt + NE;
  if (ws_size < 4 * NE * sizeof(unsigned short)) return;

  // Wb (786 KB) + xb (2 MB) live in the attn region until attn_kernel runs.
  unsigned short* Wb = attn;                          // 3 * 131072 elems
  unsigned short* xb = attn + 3 * (NH * DK * DK);     // 1,048,576 elems

  prep1_kernel<<<1408, 256, 0, stream>>>(x, Wq, Wk, Wv, xb, Wb);
  dim3 g1(8, 64);
  qkv_proj_kernel<<<g1, 256, 0, stream>>>(xb, Wb, Qw, Kw, Vt);
  attn_kernel<<<BATCH * NH * (T_SEQ / QTILE), 256, 0, stream>>>(Qw, Kw, Vt, attn);
  out_proj_kernel<<<BATCH * T_SEQ / 16, 256, 0, stream>>>(attn, Wu, bu, out);
}

// Round 9
// 210.997 us; speedup vs baseline: 1.0738x; 1.0382x over previous
//
#include <hip/hip_runtime.h>
#include <hip/hip_bf16.h>
#include <math.h>

// Problem constants: B=4, T=2048, K(head dim)=128, H=8
#define T_SEQ 2048
#define NH 8
#define DK 128
#define BATCH 4
#define KT 64     // attention KV tile
#define QTILE 128 // Q rows per block (4 waves x 32 rows)

// Q pre-scale: (1/sqrt(128)) * log2(e)  -> S feeds exp2 directly
#define QSCALE 0.1275174435f

typedef __attribute__((ext_vector_type(8))) short short8;
typedef __attribute__((ext_vector_type(4))) float floatx4;
typedef __attribute__((ext_vector_type(16))) float floatx16;
typedef __attribute__((ext_vector_type(8))) _Float16 half8;

typedef const __attribute__((address_space(1))) unsigned int gu32_t;
typedef __attribute__((address_space(3))) unsigned int lu32_t;

#if defined(__has_builtin)
#if __has_builtin(__builtin_amdgcn_exp2f)
#define EXP2F(x) __builtin_amdgcn_exp2f(x)
#endif
#endif
#ifndef EXP2F
#define EXP2F(x) exp2f(x)
#endif

__device__ __forceinline__ unsigned short f2bf(float f) {
  union { float f; unsigned u; } v; v.f = f;
  unsigned u = v.u;
  return (unsigned short)((u + 0x7fffu + ((u >> 16) & 1u)) >> 16);  // RNE
}

__device__ __forceinline__ unsigned short f2h(float f) {
  union { _Float16 h; unsigned short u; } v; v.h = (_Float16)f;
  return v.u;
}

__device__ __forceinline__ unsigned pk2bf(float a, float b) {
  __hip_bfloat162 h = __float22bfloat162_rn(make_float2(a, b));
  return *(unsigned*)&h;   // low 16 = a, high 16 = b
}

__device__ __forceinline__ unsigned pkh(float a, float b) {
  union { _Float16 h[2]; unsigned u; } v;
  v.h[0] = (_Float16)a; v.h[1] = (_Float16)b;
  return v.u;
}

// ---------------------------------------------------------------------------
// Kernel 1: fused QKV projection. grid (8 heads, 64 row-blocks), 256 thr.
// Per block: convert W tile -> LDS bf16, MFMA against in-reg x A-frags,
// stage C-tile in LDS, store COALESCED (Q/K: one contiguous 32 KB block;
// V^T: 256 B row segments). 3 phases share one 34 KB LDS buffer.
// Q pre-scaled by QSCALE; V written [B][H][128][T] fp16.
// ---------------------------------------------------------------------------
__global__ __launch_bounds__(256) void qkv_proj_kernel(
    const float* __restrict__ x, const float* __restrict__ Wq,
    const float* __restrict__ Wk, const float* __restrict__ Wv,
    unsigned short* __restrict__ Qw, unsigned short* __restrict__ Kw,
    unsigned short* __restrict__ Vt)
{
  __shared__ __align__(16) unsigned short Tile[128 * 136];   // 34.8 KB
  int h  = blockIdx.x;             // head = col block (128 cols)
  int nb = h * 128;
  int mb = blockIdx.y * 128;       // row base within 8192
  int b = mb >> 11, t0 = mb & (T_SEQ - 1);
  int t = threadIdx.x, wave = t >> 6, lane = t & 63;
  int n = lane & 15, q = lane >> 4;
  int srow = lane >> 4;            // readback row-subindex
  int scol = (lane & 15) * 8;      // readback col (shorts)

  // x A-fragments for this wave's 32 rows (fp32 -> bf16 in regs, used 3x)
  short8 xa[2][4];
  #pragma unroll
  for (int rg = 0; rg < 2; ++rg) {
    const float* xr = x + (size_t)(mb + wave*32 + rg*16 + n) * DK;
    #pragma unroll
    for (int kc = 0; kc < 4; ++kc) {
      float4 f0 = *(const float4*)(xr + kc*32 + q*8);
      float4 f1 = *(const float4*)(xr + kc*32 + q*8 + 4);
      union { short8 s; unsigned u[4]; } pk;
      pk.u[0] = pk2bf(f0.x, f0.y); pk.u[1] = pk2bf(f0.z, f0.w);
      pk.u[2] = pk2bf(f1.x, f1.y); pk.u[3] = pk2bf(f1.z, f1.w);
      xa[rg][kc] = pk.s;
    }
  }

  int crow = t >> 1, ccol0 = (t & 1) * 64;   // W-convert assignment

  for (int w = 0; w < 3; ++w) {
    const float* W = (w == 0) ? Wq : ((w == 1) ? Wk : Wv);
    float s = (w == 0) ? QSCALE : 1.0f;
    if (w) __syncthreads();        // prior store reads done
    // convert W rows nb..nb+127 (output cols), k = 0..127 -> LDS bf16
    #pragma unroll
    for (int i = 0; i < 16; ++i) {
      float4 v = *(const float4*)(W + (size_t)(nb + crow)*DK + ccol0 + i*4);
      *(uint2*)&Tile[crow*136 + ccol0 + i*4] =
          make_uint2(pk2bf(v.x*s, v.y*s), pk2bf(v.z*s, v.w*s));
    }
    __syncthreads();

    if (w < 2) {
      floatx4 acc[2][8];
      #pragma unroll
      for (int rg = 0; rg < 2; ++rg)
        #pragma unroll
        for (int cg = 0; cg < 8; ++cg)
          acc[rg][cg] = (floatx4){0.f, 0.f, 0.f, 0.f};
      #pragma unroll
      for (int kc = 0; kc < 4; ++kc)
        #pragma unroll
        for (int cg = 0; cg < 8; ++cg) {
          short8 bk = *(const short8*)&Tile[(cg*16 + n)*136 + kc*32 + q*8];
          acc[0][cg] = __builtin_amdgcn_mfma_f32_16x16x32_bf16(xa[0][kc], bk, acc[0][cg], 0, 0, 0);
          acc[1][cg] = __builtin_amdgcn_mfma_f32_16x16x32_bf16(xa[1][kc], bk, acc[1][cg], 0, 0, 0);
        }
      __syncthreads();   // all W reads done before overwrite
      #pragma unroll
      for (int rg = 0; rg < 2; ++rg)
        #pragma unroll
        for (int cg = 0; cg < 8; ++cg)
          #pragma unroll
          for (int r = 0; r < 4; ++r)
            Tile[(wave*32 + rg*16 + q*4 + r)*136 + cg*16 + n] = f2bf(acc[rg][cg][r]);
      __syncthreads();
      // coalesced store: contiguous 32 KB block (one head, 128 t-rows)
      unsigned short* gb = ((w == 0) ? Qw : Kw) +
          (((size_t)(b*NH + h))*T_SEQ + t0)*DK;
      #pragma unroll
      for (int i = 0; i < 8; ++i) {
        int row = wave*32 + i*4 + srow;
        *(uint4*)(gb + (size_t)row*DK + scol) = *(const uint4*)&Tile[row*136 + scol];
      }
    } else {
      // V: transposed C-tile (rows = d, cols = tt) via swapped operands
      floatx4 accv[8][2];
      #pragma unroll
      for (int mt = 0; mt < 8; ++mt)
        #pragma unroll
        for (int nt = 0; nt < 2; ++nt)
          accv[mt][nt] = (floatx4){0.f, 0.f, 0.f, 0.f};
      #pragma unroll
      for (int kc = 0; kc < 4; ++kc)
        #pragma unroll
        for (int mt = 0; mt < 8; ++mt) {
          short8 wa = *(const short8*)&Tile[(mt*16 + n)*136 + kc*32 + q*8];
          accv[mt][0] = __builtin_amdgcn_mfma_f32_16x16x32_bf16(wa, xa[0][kc], accv[mt][0], 0, 0, 0);
          accv[mt][1] = __builtin_amdgcn_mfma_f32_16x16x32_bf16(wa, xa[1][kc], accv[mt][1], 0, 0, 0);
        }
      __syncthreads();
      #pragma unroll
      for (int mt = 0; mt < 8; ++mt)
        #pragma unroll
        for (int nt = 0; nt < 2; ++nt)
          #pragma unroll
          for (int r = 0; r < 4; ++r)
            Tile[(mt*16 + q*4 + r)*136 + wave*32 + nt*16 + n] = f2h(accv[mt][nt][r]);
      __syncthreads();
      // coalesced store: 256 B per d-row segment
      unsigned short* gb = Vt + ((size_t)(b*NH + h))*DK*T_SEQ + t0;
      #pragma unroll
      for (int i = 0; i < 8; ++i) {
        int d = wave*32 + i*4 + srow;
        *(uint4*)(gb + (size_t)d*T_SEQ + scol) = *(const uint4*)&Tile[d*136 + scol];
      }
    }
  }
}

// ---------------------------------------------------------------------------
// Kernel 2: flash attention (UNCHANGED from round 8 — 92 µs).
// Double-buffered K/V via global_load_lds (XOR swizzle); QK^T transposed
// (32x32x16 bf16); PV full-rate 32x32x16 f16 via pairs-exchange A-frags.
// ---------------------------------------------------------------------------
__global__ __launch_bounds__(256, 2) void attn_kernel(
    const unsigned short* __restrict__ Qw, const unsigned short* __restrict__ Kw,
    const unsigned short* __restrict__ Vt, unsigned short* __restrict__ attn_out)
{
  __shared__ __align__(16) unsigned short Ks[2][KT * DK];   // 2 x 16 KB
  __shared__ __align__(16) unsigned short Vs[2][DK * KT];   // 2 x 16 KB
  int bid = blockIdx.x;
  int qt = bid & 15, h = (bid >> 4) & 7, b = bid >> 7;
  size_t base = ((size_t)(b * NH + h)) * T_SEQ * DK;
  const unsigned short* Qb = Qw + base;
  const unsigned short* Kb = Kw + base;
  const unsigned short* Vb = Vt + base;   // [128][2048] fp16
  int t = threadIdx.x, w = t >> 6, lane = t & 63;
  int l31 = lane & 31, l15 = lane & 15, hi = lane >> 5;
  bool hb = (hi != 0);

  short8 qf[8];
  {
    const unsigned short* qr = Qb + (size_t)(qt*QTILE + w*32 + l31) * DK;
    #pragma unroll
    for (int kc = 0; kc < 8; ++kc)
      qf[kc] = *(const short8*)(qr + kc*16 + hi*8);
  }
  floatx16 Oacc[4];
  #pragma unroll
  for (int dt = 0; dt < 4; ++dt)
    #pragma unroll
    for (int r = 0; r < 16; ++r) Oacc[dt][r] = 0.f;
  float lp = 0.f;

  int kkey_lo = lane >> 4;
  int kck     = lane & 15;
  int vd_lo   = lane >> 3;
  int vck     = lane & 7;
  int cv      = vck ^ vd_lo;

  #define STAGE(KTI, BUFI)                                                      \
    {                                                                           \
      _Pragma("unroll")                                                         \
      for (int j = 0; j < 4; ++j) {                                             \
        int inst = w*4 + j;                                                     \
        int key = inst*4 + kkey_lo;                                             \
        int ck = kck ^ (key & 15);                                              \
        __builtin_amdgcn_global_load_lds(                                       \
            (gu32_t*)(Kb + ((size_t)((KTI)*KT + key))*DK + ck*8),               \
            (lu32_t*)(&Ks[BUFI][inst*512]), 16, 0, 0);                          \
        int d = inst*8 + vd_lo;                                                 \
        __builtin_amdgcn_global_load_lds(                                       \
            (gu32_t*)(Vb + (size_t)d*T_SEQ + (KTI)*KT + cv*8),                  \
            (lu32_t*)(&Vs[BUFI][inst*512]), 16, 0, 0);                          \
      }                                                                         \
    }

  STAGE(0, 0);

  for (int kt = 0; kt < T_SEQ / KT; ++kt) {
    __syncthreads();
    int buf = kt & 1;
    if (kt + 1 < T_SEQ / KT) STAGE(kt + 1, buf ^ 1);

    const unsigned short* KsL = &Ks[buf][0];
    const unsigned short* VsL = &Vs[buf][0];

    floatx16 st0, st1;
    #pragma unroll
    for (int r = 0; r < 16; ++r) { st0[r] = 0.f; st1[r] = 0.f; }
    #pragma unroll
    for (int kc = 0; kc < 8; ++kc) {
      int cp = (2*kc + hi) ^ l15;
      short8 ak0 = *(const short8*)&KsL[(      l31)*DK + cp*8];
      short8 ak1 = *(const short8*)&KsL[(32 + l31)*DK + cp*8];
      st0 = __builtin_amdgcn_mfma_f32_32x32x16_bf16(ak0, qf[kc], st0, 0, 0, 0);
      st1 = __builtin_amdgcn_mfma_f32_32x32x16_bf16(ak1, qf[kc], st1, 0, 0, 0);
    }
    #pragma unroll
    for (int g = 0; g < 2; ++g) {
      const floatx16& st = g ? st1 : st0;
      float e[16];
      #pragma unroll
      for (int r = 0; r < 16; ++r) e[r] = EXP2F(st[r]);
      float s = 0.f;
      #pragma unroll
      for (int r = 0; r < 16; ++r) s += e[r];
      lp += s;
      unsigned p[8];
      #pragma unroll
      for (int i = 0; i < 8; ++i) p[i] = pkh(e[2*i], e[2*i + 1]);
      #pragma unroll
      for (int m = 0; m < 2; ++m) {
        unsigned lo0 = p[4*m], lo1 = p[4*m + 1];
        unsigned up0 = p[4*m + 2], up1 = p[4*m + 3];
        unsigned s0 = hb ? lo0 : up0;
        unsigned s1 = hb ? lo1 : up1;
        unsigned r0 = __shfl_xor(s0, 32, 64);
        unsigned r1 = __shfl_xor(s1, 32, 64);
        union { half8 hv; unsigned u[4]; } fm;
        fm.u[0] = hb ? r0 : lo0;
        fm.u[1] = hb ? r1 : lo1;
        fm.u[2] = hb ? up0 : r0;
        fm.u[3] = hb ? up1 : r1;
        int cp = (4*g + 2*m + hi) ^ (l31 & 7);
        #pragma unroll
        for (int dt = 0; dt < 4; ++dt) {
          int d = dt*32 + l31;
          half8 bv = *(const half8*)&VsL[d*KT + cp*8];
          Oacc[dt] = __builtin_amdgcn_mfma_f32_32x32x16_f16(fm.hv, bv, Oacc[dt], 0, 0, 0);
        }
      }
    }
  }
  float lpt = lp + __shfl_xor(lp, 32, 64);
  float rinv = 1.0f / lpt;
  float ri[16];
  #pragma unroll
  for (int r = 0; r < 16; ++r) {
    int row = (r & 3) + 8*(r >> 2) + 4*hi;
    ri[r] = __shfl(rinv, row, 64);
  }
  #pragma unroll
  for (int dt = 0; dt < 4; ++dt)
    #pragma unroll
    for (int r = 0; r < 16; ++r) {
      int row = (r & 3) + 8*(r >> 2) + 4*hi;
      int trow = qt*QTILE + w*32 + row;
      int col  = h*DK + dt*32 + l31;
      attn_out[((size_t)b*T_SEQ + trow)*1024 + col] = f2bf(Oacc[dt][r] * ri[r]);
    }
}

// ---------------------------------------------------------------------------
// Kernel 3: out = attn(8192,1024)bf16 @ Wu^T + bu. LDS-free; Wu read fp32
// from L2, converted to bf16 in-register. grid = 512 blocks (16 rows each).
// ---------------------------------------------------------------------------
__global__ __launch_bounds__(256) void out_proj_kernel(
    const unsigned short* __restrict__ attnb, const float* __restrict__ Wu,
    const float* __restrict__ bu, float* __restrict__ out)
{
  int mb = blockIdx.x * 16;
  int t = threadIdx.x, wave = t >> 6, lane = t & 63;
  int n = lane & 15, q = lane >> 4;
  int nb2 = wave * 32;
  floatx4 acc[2];
  acc[0] = (floatx4){0.f,0.f,0.f,0.f};
  acc[1] = (floatx4){0.f,0.f,0.f,0.f};
  const unsigned short* ap = attnb + (size_t)(mb + n) * 1024;
  #pragma unroll 4
  for (int kc = 0; kc < 32; ++kc) {
    int ko = kc*32 + q*8;
    short8 a0 = *(const short8*)(ap + ko);
    #pragma unroll
    for (int cg = 0; cg < 2; ++cg) {
      const float* wr = Wu + (size_t)(nb2 + cg*16 + n) * 1024 + ko;
      float4 w0 = *(const float4*)(wr);
      float4 w1 = *(const float4*)(wr + 4);
      union { short8 s; unsigned u[4]; } bw;
      bw.u[0] = pk2bf(w0.x, w0.y); bw.u[1] = pk2bf(w0.z, w0.w);
      bw.u[2] = pk2bf(w1.x, w1.y); bw.u[3] = pk2bf(w1.z, w1.w);
      acc[cg] = __builtin_amdgcn_mfma_f32_16x16x32_bf16(a0, bw.s, acc[cg], 0, 0, 0);
    }
  }
  #pragma unroll
  for (int cg = 0; cg < 2; ++cg)
    #pragma unroll
    for (int r = 0; r < 4; ++r) {
      int m = mb + q*4 + r;
      int c = nb2 + cg*16 + n;
      out[(size_t)m * 128 + c] = acc[cg][r] + bu[c];
    }
}

// ---------------------------------------------------------------------------
extern "C" void kernel_launch(void* const* d_in, const int* in_sizes, int n_in,
                              void* d_out, int out_size, void* d_ws, size_t ws_size,
                              hipStream_t stream) {
  const float* x  = (const float*)d_in[0];
  const float* Wq = (const float*)d_in[1];
  const float* Wk = (const float*)d_in[2];
  const float* Wv = (const float*)d_in[3];
  const float* Wu = (const float*)d_in[4];
  const float* bu = (const float*)d_in[5];
  float* out = (float*)d_out;

  const size_t NE = (size_t)BATCH * NH * T_SEQ * DK;  // 8,388,608 elems
  unsigned short* Qw = (unsigned short*)d_ws;
  unsigned short* Kw = Qw + NE;
  unsigned short* Vt = Kw + NE;
  unsigned short* attn = Vt + NE;
  if (ws_size < 4 * NE * sizeof(unsigned short)) return;

  dim3 g1(8, 64);
  qkv_proj_kernel<<<g1, 256, 0, stream>>>(x, Wq, Wk, Wv, Qw, Kw, Vt);
  attn_kernel<<<BATCH * NH * (T_SEQ / QTILE), 256, 0, stream>>>(Qw, Kw, Vt, attn);
  out_proj_kernel<<<BATCH * T_SEQ / 16, 256, 0, stream>>>(attn, Wu, bu, out);
}